// Round 1
// baseline (254.625 us; speedup 1.0000x reference)
//
#include <hip/hip_runtime.h>
#include <math.h>

// Problem constants (fixed by the reference)
constexpr int Bn  = 32;
constexpr int Cn  = 256;
constexpr int Hn  = 64;
constexpr int Wn  = 64;
constexpr int HW  = Hn * Wn;        // 4096
constexpr int CHW = Cn * HW;        // 1048576
constexpr int HW4 = HW / 4;         // 1024 float4 per (b,c) plane
constexpr int NPOS  = Bn * HW;      // 131072 spatial positions
constexpr int NPOS4 = NPOS / 4;     // 32768 float4 positions

// -------------------------------------------------------------------------
// Kernel 1: channel-wise max + mean.
// Block = 256 threads = 4 waves. Wave `chunk` reduces channels
// [chunk*64, chunk*64+64) for 64 consecutive float4 spatial positions.
// Each load: 64 lanes x 16 B contiguous = 1 KiB coalesced.
// LDS combine across the 4 chunks; wave 0 writes results.
// -------------------------------------------------------------------------
__global__ __launch_bounds__(256) void reduce_k(const float* __restrict__ x,
                                                float* __restrict__ pmax,
                                                float* __restrict__ pavg) {
    __shared__ float4 smax[4][64];
    __shared__ float4 ssum[4][64];

    const int lane  = threadIdx.x & 63;
    const int chunk = threadIdx.x >> 6;           // 0..3 (wave id)
    const int pos4  = blockIdx.x * 64 + lane;     // global float4 position, 0..32767
    const int b     = pos4 >> 10;                 // / HW4 (block never straddles b)
    const int sp4   = pos4 & (HW4 - 1);

    const float4* xp = (const float4*)x + (size_t)b * (CHW / 4)
                       + (size_t)(chunk * 64) * HW4 + sp4;

    float4 mx = make_float4(-INFINITY, -INFINITY, -INFINITY, -INFINITY);
    float4 sm = make_float4(0.f, 0.f, 0.f, 0.f);

    #pragma unroll 8
    for (int c = 0; c < 64; ++c) {
        float4 v = xp[(size_t)c * HW4];
        mx.x = fmaxf(mx.x, v.x); mx.y = fmaxf(mx.y, v.y);
        mx.z = fmaxf(mx.z, v.z); mx.w = fmaxf(mx.w, v.w);
        sm.x += v.x; sm.y += v.y; sm.z += v.z; sm.w += v.w;
    }

    smax[chunk][lane] = mx;
    ssum[chunk][lane] = sm;
    __syncthreads();

    if (chunk == 0) {
        float4 M = smax[0][lane];
        float4 S = ssum[0][lane];
        #pragma unroll
        for (int k = 1; k < 4; ++k) {
            float4 m2 = smax[k][lane];
            float4 s2 = ssum[k][lane];
            M.x = fmaxf(M.x, m2.x); M.y = fmaxf(M.y, m2.y);
            M.z = fmaxf(M.z, m2.z); M.w = fmaxf(M.w, m2.w);
            S.x += s2.x; S.y += s2.y; S.z += s2.z; S.w += s2.w;
        }
        const float inv = 1.0f / (float)Cn;
        float4 A = make_float4(S.x * inv, S.y * inv, S.z * inv, S.w * inv);
        ((float4*)pmax)[pos4] = M;
        ((float4*)pavg)[pos4] = A;
    }
}

// -------------------------------------------------------------------------
// Kernel 2: 7x7 conv (cross-correlation, zero-pad 3) over [max, avg] + sigmoid.
// One thread per spatial position. Weights (98 floats) staged in LDS.
// Pooled arrays are 1 MB total -> L2-resident; this kernel is tiny.
// -------------------------------------------------------------------------
__global__ __launch_bounds__(256) void conv_k(const float* __restrict__ pmax,
                                              const float* __restrict__ pavg,
                                              const float* __restrict__ w,
                                              float* __restrict__ scale) {
    __shared__ float sw[98];
    if (threadIdx.x < 98) sw[threadIdx.x] = w[threadIdx.x];
    __syncthreads();

    const int idx = blockIdx.x * blockDim.x + threadIdx.x;   // 0..131071
    const int b   = idx >> 12;           // / 4096
    const int sp  = idx & 4095;
    const int h   = sp >> 6;
    const int wc  = sp & 63;

    const float* pm = pmax + b * HW;
    const float* pa = pavg + b * HW;

    float acc = 0.f;
    #pragma unroll
    for (int kh = 0; kh < 7; ++kh) {
        const int hh = h + kh - 3;
        if (hh < 0 || hh >= Hn) continue;
        #pragma unroll
        for (int kw = 0; kw < 7; ++kw) {
            const int ww = wc + kw - 3;
            if (ww < 0 || ww >= Wn) continue;
            const int o = hh * Wn + ww;
            acc += pm[o] * sw[kh * 7 + kw] + pa[o] * sw[49 + kh * 7 + kw];
        }
    }
    scale[idx] = 1.f / (1.f + expf(-acc));
}

// -------------------------------------------------------------------------
// Kernel 3: out = x * scale (broadcast over channels). Flat float4 stream.
// scale plane (4 KB per batch) re-reads hit L1/L2.
// -------------------------------------------------------------------------
__global__ __launch_bounds__(256) void mul_k(const float* __restrict__ x,
                                             const float* __restrict__ scale,
                                             float* __restrict__ out) {
    const long long i4 = (long long)blockIdx.x * 256 + threadIdx.x;  // 0..8388607
    const int b   = (int)(i4 >> 18);       // / (CHW/4 = 262144)
    const int hw4 = (int)(i4 & (HW4 - 1));

    const float4 s = ((const float4*)scale)[b * HW4 + hw4];
    const float4 v = ((const float4*)x)[i4];
    float4 o;
    o.x = v.x * s.x; o.y = v.y * s.y; o.z = v.z * s.z; o.w = v.w * s.w;
    ((float4*)out)[i4] = o;
}

extern "C" void kernel_launch(void* const* d_in, const int* in_sizes, int n_in,
                              void* d_out, int out_size, void* d_ws, size_t ws_size,
                              hipStream_t stream) {
    const float* x = (const float*)d_in[0];
    const float* w = (const float*)d_in[1];
    float* out = (float*)d_out;

    // Workspace layout (floats): pmax[NPOS] | pavg[NPOS] | scale[NPOS]  = 1.5 MB
    float* pmax  = (float*)d_ws;
    float* pavg  = pmax + NPOS;
    float* scale = pavg + NPOS;

    // Pass 1: channel max/mean. 512 blocks x 256 thr (4 waves, 64-ch chunks each).
    reduce_k<<<NPOS4 / 64, 256, 0, stream>>>(x, pmax, pavg);

    // Pass 2: 7x7 conv + sigmoid. 512 blocks x 256 thr.
    conv_k<<<NPOS / 256, 256, 0, stream>>>(pmax, pavg, w, scale);

    // Pass 3: broadcast multiply. 32768 blocks x 256 thr (float4 per thread).
    mul_k<<<(Bn * CHW / 4) / 256, 256, 0, stream>>>(x, scale, out);
}